// Round 11
// baseline (1319.634 us; speedup 1.0000x reference)
//
#include <hip/hip_runtime.h>

#define DIM 128
#define NPB 32            // nodes per block in CSR-fallback fused
#define SCAN_CHUNK 1024   // nodes per scanA block (fallback)
#define PART_T 64         // edges per thread in partition
#define PART_EB (256 * PART_T)  // 16384 edges per partition block
#define BK_BITS 6         // 64-node buckets (main path)

typedef unsigned int   uint32;
typedef unsigned short uint16;

__device__ __forceinline__ uint16 f32_to_bf16_rne(float f) {
    uint32 u = __float_as_uint(f);
    u += 0x7fffu + ((u >> 16) & 1u);
    return (uint16)(u >> 16);
}

// ===========================================================================
// prep: [0,64) transpose W ; [64,64+nConv) h->bf16 ; rest: per-node histogram
// ===========================================================================
__global__ __launch_bounds__(256) void prep_kernel(
    const float* __restrict__ W, float* __restrict__ Wt,
    const float* __restrict__ h, uint16* __restrict__ hb,
    const int* __restrict__ dst, int* __restrict__ cnt,
    int E, long long ND, int nConv, int doConv)
{
    const int bid = blockIdx.x;
    const int tid = threadIdx.x;
    if (bid < 64) {
        const int i = bid * 256 + tid;
        const int j = i >> 7, d = i & 127;
        Wt[d * DIM + j] = W[i];
    } else if (doConv && bid < 64 + nConv) {
        const long long base = ((long long)(bid - 64) * 256 + tid) * 8;
        if (base + 8 <= ND) {
            const float4 a = *(const float4*)&h[base];
            const float4 c = *(const float4*)&h[base + 4];
            uint4 v;
            v.x = (uint32)f32_to_bf16_rne(a.x) | ((uint32)f32_to_bf16_rne(a.y) << 16);
            v.y = (uint32)f32_to_bf16_rne(a.z) | ((uint32)f32_to_bf16_rne(a.w) << 16);
            v.z = (uint32)f32_to_bf16_rne(c.x) | ((uint32)f32_to_bf16_rne(c.y) << 16);
            v.w = (uint32)f32_to_bf16_rne(c.z) | ((uint32)f32_to_bf16_rne(c.w) << 16);
            *(uint4*)&hb[base] = v;
        }
    } else {
        const int hbase = 64 + (doConv ? nConv : 0);
        const long long e = ((long long)(bid - hbase) * 256 + tid) * 4;
        if (e + 4 <= E) {
            const int4 d4 = *(const int4*)&dst[e];
            atomicAdd(&cnt[d4.x], 1);
            atomicAdd(&cnt[d4.y], 1);
            atomicAdd(&cnt[d4.z], 1);
            atomicAdd(&cnt[d4.w], 1);
        } else {
            for (long long k = e; k < E && k < e + 4; ++k) atomicAdd(&cnt[dst[k]], 1);
        }
    }
}

// ---- bucketsum: 16-thread group sums 64 node degrees -> bsumB[bk] ---------
__global__ __launch_bounds__(256) void bucketsum_kernel(
    const int* __restrict__ cnt, int* __restrict__ bsumB, int N, int nbuck)
{
    const int t = threadIdx.x;
    const int bk = blockIdx.x * 16 + (t >> 4);
    const int l  = t & 15;
    int v = 0;
    const int base = bk * 64 + l * 4;
#pragma unroll
    for (int k = 0; k < 4; ++k) {
        const int idx = base + k;
        if (bk < nbuck && idx < N) v += cnt[idx];
    }
#pragma unroll
    for (int o = 8; o >= 1; o >>= 1) v += __shfl_xor(v, o, 16);
    if ((t & 15) == 0 && bk < nbuck) bsumB[bk] = v;
}

// ---- scanS: exclusive scan of bucket sums -> gptr (mutable) + bstart ------
__global__ __launch_bounds__(1024) void scanS_kernel(
    const int* __restrict__ bsumB, int* __restrict__ gptr,
    int* __restrict__ bstart, int nbuck)
{
    __shared__ int ts[1024];
    const int t = threadIdx.x;
    const int b0 = 2 * t, b1 = 2 * t + 1;
    const int s0 = (b0 < nbuck) ? bsumB[b0] : 0;
    const int s1 = (b1 < nbuck) ? bsumB[b1] : 0;
    ts[t] = s0 + s1;
    __syncthreads();
    for (int off = 1; off < 1024; off <<= 1) {
        int x = (t >= off) ? ts[t - off] : 0;
        __syncthreads();
        ts[t] += x;
        __syncthreads();
    }
    const int base = (t == 0) ? 0 : ts[t - 1];
    if (b0 < nbuck) { gptr[b0] = base;      bstart[b0] = base; }
    if (b1 < nbuck) { gptr[b1] = base + s0; bstart[b1] = base + s0; }
}

// ---- partition: LDS-staged radix partition into 64-node buckets -----------
// Packed edge word: src (bits 0..19) | dstLocal (bits 20..25).
__global__ __launch_bounds__(256) void partition64_kernel(
    const int* __restrict__ src, const int* __restrict__ dst,
    int* __restrict__ gptr, uint32* __restrict__ ebuf, int E, int nbuck)
{
    __shared__ int hist[2048];
    const int t = threadIdx.x;
    const long long e0 = (long long)blockIdx.x * PART_EB;

    for (int i = t; i < 2048; i += 256) hist[i] = 0;
    __syncthreads();

#pragma unroll 1
    for (int j = 0; j < PART_T / 4; ++j) {
        const long long be = e0 + ((long long)(j * 256 + t)) * 4;
        if (be + 4 <= E) {
            const int4 d4 = *(const int4*)&dst[be];
            atomicAdd(&hist[d4.x >> BK_BITS], 1);
            atomicAdd(&hist[d4.y >> BK_BITS], 1);
            atomicAdd(&hist[d4.z >> BK_BITS], 1);
            atomicAdd(&hist[d4.w >> BK_BITS], 1);
        } else {
            for (long long k = be; k < E && k < be + 4; ++k)
                atomicAdd(&hist[dst[k] >> BK_BITS], 1);
        }
    }
    __syncthreads();

    for (int i = t; i < nbuck; i += 256) {
        const int c = hist[i];
        hist[i] = (c > 0) ? atomicAdd(&gptr[i], c) : 0;
    }
    __syncthreads();

#pragma unroll 1
    for (int j = 0; j < PART_T / 4; ++j) {
        const long long be = e0 + ((long long)(j * 256 + t)) * 4;
        if (be + 4 <= E) {
            const int4 s4 = *(const int4*)&src[be];
            const int4 d4 = *(const int4*)&dst[be];
            int sl;
            sl = atomicAdd(&hist[d4.x >> BK_BITS], 1);
            ebuf[sl] = (uint32)s4.x | ((uint32)(d4.x & 63) << 20);
            sl = atomicAdd(&hist[d4.y >> BK_BITS], 1);
            ebuf[sl] = (uint32)s4.y | ((uint32)(d4.y & 63) << 20);
            sl = atomicAdd(&hist[d4.z >> BK_BITS], 1);
            ebuf[sl] = (uint32)s4.z | ((uint32)(d4.z & 63) << 20);
            sl = atomicAdd(&hist[d4.w >> BK_BITS], 1);
            ebuf[sl] = (uint32)s4.w | ((uint32)(d4.w & 63) << 20);
        } else {
            for (long long k = be; k < E && k < be + 4; ++k) {
                const int d = dst[k];
                const int sl = atomicAdd(&hist[d >> BK_BITS], 1);
                ebuf[sl] = (uint32)src[k] | ((uint32)(d & 63) << 20);
            }
        }
    }
}

// ===========================================================================
// Main fused kernel: one block per 64-node bucket, 8 waves.
//   Edge loop: each wave takes every 8th edge; 64 lanes read the source row
//   (bf16, dword/lane) and LDS-float-atomicAdd into sums[dstLocal].
//   Then normalize (mean or h-fallback) + GEMM (round-8 shape, 8 nodes/wave).
//   NOTE: #pragma unroll 1 on the d4 GEMM loop is load-bearing — full unroll
//   blows past 256 VGPRs and spills ~3.5 GB to scratch (rounds 2-3).
// ===========================================================================
__global__ __launch_bounds__(512) void fused512_bf(
    const float* __restrict__ h, const uint16* __restrict__ hb,
    const int* __restrict__ cnt, const int* __restrict__ bstart,
    const int* __restrict__ gptr, const uint32* __restrict__ ebuf,
    const float* __restrict__ Wt, const float* __restrict__ bias,
    float* __restrict__ out, int N)
{
    __shared__ float sums[64][DIM];   // 32 KB
    const int t = threadIdx.x;
    const int lane = t & 63;
    const int w = t >> 6;             // 0..7
    const int col2 = lane * 2;
    const int b = blockIdx.x;

#pragma unroll
    for (int k = 0; k < 16; ++k) ((float*)sums)[t + k * 512] = 0.0f;
    __syncthreads();

    const int start = bstart[b];
    const int end   = gptr[b];        // final append pointer after partition
#pragma unroll 1
    for (int i = start + w; i < end; i += 8) {
        const uint32 p = ebuf[i];
        const int s    = (int)(p & 0xFFFFFu);
        const int dloc = (int)(p >> 20);
        const uint32 u = *(const uint32*)&hb[(size_t)s * DIM + col2];
        atomicAdd(&sums[dloc][col2],     __uint_as_float(u << 16));
        atomicAdd(&sums[dloc][col2 + 1], __uint_as_float(u & 0xffff0000u));
    }
    __syncthreads();

    // normalize my 8 rows (wave-private; no further barrier needed)
    const int nbase = b * 64 + w * 8;
#pragma unroll
    for (int j = 0; j < 8; ++j) {
        const int node = nbase + j;
        if (node >= N) continue;
        const int deg = cnt[node];
        float2 v;
        if (deg == 0) {
            v = *(const float2*)&h[(size_t)node * DIM + col2];
        } else {
            const float inv = 1.0f / (float)deg;
            v = make_float2(sums[w * 8 + j][col2] * inv,
                            sums[w * 8 + j][col2 + 1] * inv);
        }
        *(float2*)&sums[w * 8 + j][col2] = v;
    }

    const float2 bb = *(const float2*)&bias[col2];
    float acc0[8], acc1[8];
#pragma unroll
    for (int n = 0; n < 8; ++n) { acc0[n] = bb.x; acc1[n] = bb.y; }

#pragma unroll 1
    for (int d4 = 0; d4 < DIM; d4 += 4) {
        float4 a[8];
#pragma unroll
        for (int n = 0; n < 8; ++n)
            a[n] = *(const float4*)&sums[w * 8 + n][d4];   // broadcast
#pragma unroll
        for (int dd = 0; dd < 4; ++dd) {
            const float2 wt = *(const float2*)&Wt[(d4 + dd) * DIM + col2];
#pragma unroll
            for (int n = 0; n < 8; ++n) {
                const float av = dd == 0 ? a[n].x : dd == 1 ? a[n].y
                               : dd == 2 ? a[n].z : a[n].w;
                acc0[n] = fmaf(av, wt.x, acc0[n]);
                acc1[n] = fmaf(av, wt.y, acc1[n]);
            }
        }
    }

#pragma unroll
    for (int n = 0; n < 8; ++n) {
        const int node = nbase + n;
        if (node < N) {
            *(float2*)&out[(size_t)node * DIM + col2] =
                make_float2(fmaxf(acc0[n], 0.0f), fmaxf(acc1[n], 0.0f));
        }
    }
}

// ---- f32-gather bucket variant (ws fits ebuf but not hb) ------------------
__global__ __launch_bounds__(512) void fused512_f32(
    const float* __restrict__ h, const int* __restrict__ cnt,
    const int* __restrict__ bstart, const int* __restrict__ gptr,
    const uint32* __restrict__ ebuf, const float* __restrict__ Wt,
    const float* __restrict__ bias, float* __restrict__ out, int N)
{
    __shared__ float sums[64][DIM];
    const int t = threadIdx.x;
    const int lane = t & 63;
    const int w = t >> 6;
    const int col2 = lane * 2;
    const int b = blockIdx.x;

#pragma unroll
    for (int k = 0; k < 16; ++k) ((float*)sums)[t + k * 512] = 0.0f;
    __syncthreads();

    const int start = bstart[b];
    const int end   = gptr[b];
#pragma unroll 1
    for (int i = start + w; i < end; i += 8) {
        const uint32 p = ebuf[i];
        const int s    = (int)(p & 0xFFFFFu);
        const int dloc = (int)(p >> 20);
        const float2 hv = *(const float2*)&h[(size_t)s * DIM + col2];
        atomicAdd(&sums[dloc][col2],     hv.x);
        atomicAdd(&sums[dloc][col2 + 1], hv.y);
    }
    __syncthreads();

    const int nbase = b * 64 + w * 8;
#pragma unroll
    for (int j = 0; j < 8; ++j) {
        const int node = nbase + j;
        if (node >= N) continue;
        const int deg = cnt[node];
        float2 v;
        if (deg == 0) {
            v = *(const float2*)&h[(size_t)node * DIM + col2];
        } else {
            const float inv = 1.0f / (float)deg;
            v = make_float2(sums[w * 8 + j][col2] * inv,
                            sums[w * 8 + j][col2 + 1] * inv);
        }
        *(float2*)&sums[w * 8 + j][col2] = v;
    }

    const float2 bb = *(const float2*)&bias[col2];
    float acc0[8], acc1[8];
#pragma unroll
    for (int n = 0; n < 8; ++n) { acc0[n] = bb.x; acc1[n] = bb.y; }

#pragma unroll 1
    for (int d4 = 0; d4 < DIM; d4 += 4) {
        float4 a[8];
#pragma unroll
        for (int n = 0; n < 8; ++n)
            a[n] = *(const float4*)&sums[w * 8 + n][d4];
#pragma unroll
        for (int dd = 0; dd < 4; ++dd) {
            const float2 wt = *(const float2*)&Wt[(d4 + dd) * DIM + col2];
#pragma unroll
            for (int n = 0; n < 8; ++n) {
                const float av = dd == 0 ? a[n].x : dd == 1 ? a[n].y
                               : dd == 2 ? a[n].z : a[n].w;
                acc0[n] = fmaf(av, wt.x, acc0[n]);
                acc1[n] = fmaf(av, wt.y, acc1[n]);
            }
        }
    }

#pragma unroll
    for (int n = 0; n < 8; ++n) {
        const int node = nbase + n;
        if (node < N) {
            *(float2*)&out[(size_t)node * DIM + col2] =
                make_float2(fmaxf(acc0[n], 0.0f), fmaxf(acc1[n], 0.0f));
        }
    }
}

// ===========================================================================
// CSR fallback path (only if ws can't hold ebuf) — round-6 proven kernels
// ===========================================================================
__global__ __launch_bounds__(256) void scanA_kernel(const int* __restrict__ cnt,
                                                    int* __restrict__ pos,
                                                    int* __restrict__ bsum, int N)
{
    __shared__ int ts[256];
    const int t = threadIdx.x;
    const int base = blockIdx.x * SCAN_CHUNK + t * 4;
    int v[4];
    int s = 0;
#pragma unroll
    for (int k = 0; k < 4; ++k) {
        v[k] = (base + k < N) ? cnt[base + k] : 0;
        s += v[k];
    }
    ts[t] = s;
    __syncthreads();
    for (int off = 1; off < 256; off <<= 1) {
        int x = (t >= off) ? ts[t - off] : 0;
        __syncthreads();
        ts[t] += x;
        __syncthreads();
    }
    int run = (t == 0) ? 0 : ts[t - 1];
    if (t == 255) bsum[blockIdx.x] = ts[255];
#pragma unroll
    for (int k = 0; k < 4; ++k) {
        if (base + k < N) pos[base + k] = run;
        run += v[k];
    }
}

__global__ __launch_bounds__(1024) void scanB_fb_kernel(int* __restrict__ bsum, int nb)
{
    __shared__ int ts[1024];
    const int t = threadIdx.x;
    ts[t] = (t < nb) ? bsum[t] : 0;
    __syncthreads();
    for (int off = 1; off < 1024; off <<= 1) {
        int x = (t >= off) ? ts[t - off] : 0;
        __syncthreads();
        ts[t] += x;
        __syncthreads();
    }
    if (t < nb) bsum[t] = (t == 0) ? 0 : ts[t - 1];
}

__global__ __launch_bounds__(256) void fill_direct_kernel(
    const int* __restrict__ src, const int* __restrict__ dst,
    int* __restrict__ pos, const int* __restrict__ bsum,
    int* __restrict__ esrc, int E)
{
    const long long e = ((long long)blockIdx.x * 256 + threadIdx.x) * 4;
    if (e + 4 <= E) {
        const int4 s4 = *(const int4*)&src[e];
        const int4 d4 = *(const int4*)&dst[e];
        int sl;
        sl = atomicAdd(&pos[d4.x], 1); esrc[sl + bsum[d4.x >> 10]] = s4.x;
        sl = atomicAdd(&pos[d4.y], 1); esrc[sl + bsum[d4.y >> 10]] = s4.y;
        sl = atomicAdd(&pos[d4.z], 1); esrc[sl + bsum[d4.z >> 10]] = s4.z;
        sl = atomicAdd(&pos[d4.w], 1); esrc[sl + bsum[d4.w >> 10]] = s4.w;
    } else {
        for (long long k = e; k < E && k < e + 4; ++k) {
            const int d = dst[k];
            const int sl = atomicAdd(&pos[d], 1);
            esrc[sl + bsum[d >> 10]] = src[k];
        }
    }
}

__global__ __launch_bounds__(256) void fused_kernel_f32(
    const float* __restrict__ h,
    const int* __restrict__ cnt, const int* __restrict__ pos,
    const int* __restrict__ bsum, const int* __restrict__ esrc,
    const float* __restrict__ Wt, const float* __restrict__ bias,
    float* __restrict__ out, int N)
{
    __shared__ float row_lds[NPB][DIM];
    const int lane = threadIdx.x & 63;
    const int w    = threadIdx.x >> 6;
    const int nbase = blockIdx.x * NPB + w * 8;
    const int col2 = lane * 2;

#pragma unroll 1
    for (int i = 0; i < 8; ++i) {
        const int node = nbase + i;
        if (node >= N) break;
        const int deg = cnt[node];
        float ax, ay;
        if (deg == 0) {
            const float2 v = *(const float2*)&h[(size_t)node * DIM + col2];
            ax = v.x; ay = v.y;
        } else {
            const int start = pos[node] - deg + bsum[node >> 10];
            ax = 0.f; ay = 0.f;
#pragma unroll 4
            for (int k = 0; k < deg; ++k) {
                const int s = esrc[start + k];
                const float2 v = *(const float2*)&h[(size_t)s * DIM + col2];
                ax += v.x; ay += v.y;
            }
            const float inv = 1.0f / (float)deg;
            ax *= inv; ay *= inv;
        }
        *(float2*)&row_lds[w * 8 + i][col2] = make_float2(ax, ay);
    }
    __syncthreads();

    const float2 bb = *(const float2*)&bias[col2];
    float acc0[8], acc1[8];
#pragma unroll
    for (int n = 0; n < 8; ++n) { acc0[n] = bb.x; acc1[n] = bb.y; }

#pragma unroll 1
    for (int d4 = 0; d4 < DIM; d4 += 4) {
        float4 a[8];
#pragma unroll
        for (int n = 0; n < 8; ++n)
            a[n] = *(const float4*)&row_lds[w * 8 + n][d4];
#pragma unroll
        for (int dd = 0; dd < 4; ++dd) {
            const float2 wt = *(const float2*)&Wt[(d4 + dd) * DIM + col2];
#pragma unroll
            for (int n = 0; n < 8; ++n) {
                const float av = dd == 0 ? a[n].x : dd == 1 ? a[n].y
                               : dd == 2 ? a[n].z : a[n].w;
                acc0[n] = fmaf(av, wt.x, acc0[n]);
                acc1[n] = fmaf(av, wt.y, acc1[n]);
            }
        }
    }

#pragma unroll
    for (int n = 0; n < 8; ++n) {
        const int node = nbase + n;
        if (node < N) {
            *(float2*)&out[(size_t)node * DIM + col2] =
                make_float2(fmaxf(acc0[n], 0.0f), fmaxf(acc1[n], 0.0f));
        }
    }
}

// ===========================================================================
extern "C" void kernel_launch(void* const* d_in, const int* in_sizes, int n_in,
                              void* d_out, int out_size, void* d_ws, size_t ws_size,
                              hipStream_t stream)
{
    const float* h  = (const float*)d_in[0];
    const int* src  = (const int*)d_in[1];
    const int* dst  = (const int*)d_in[2];
    const float* W  = (const float*)d_in[3];
    const float* b  = (const float*)d_in[4];
    float* out = (float*)d_out;

    const int N = in_sizes[0] / DIM;
    const int E = in_sizes[1];
    const long long ND = (long long)N * DIM;
    const int nbuck = (N + 63) >> BK_BITS;             // 64-node buckets

    // Workspace layout (main path first, fallback overlays ebuf/hb region)
    const size_t off_cnt   = 0;
    const size_t off_wt    = (size_t)N * sizeof(int);
    const size_t off_bsumB = off_wt + (size_t)DIM * DIM * sizeof(float);
    const size_t off_gptr  = off_bsumB + 2048 * sizeof(int);
    const size_t off_bst   = off_gptr + 2048 * sizeof(int);
    const size_t off_ebuf  = (off_bst + 2048 * sizeof(int) + 255) & ~(size_t)255;
    const size_t off_hb    = (off_ebuf + (size_t)E * sizeof(uint32) + 255) & ~(size_t)255;
    const size_t req_bkt   = off_hb;                               // bucket path, f32 gather
    const size_t req_main  = off_hb + (size_t)ND * sizeof(uint16); // + bf16 copy

    int*    cnt    = (int*)((char*)d_ws + off_cnt);
    float*  Wt     = (float*)((char*)d_ws + off_wt);
    int*    bsumB  = (int*)((char*)d_ws + off_bsumB);
    int*    gptr   = (int*)((char*)d_ws + off_gptr);
    int*    bstart = (int*)((char*)d_ws + off_bst);
    uint32* ebuf   = (uint32*)((char*)d_ws + off_ebuf);
    uint16* hb     = (uint16*)((char*)d_ws + off_hb);
    // fallback overlays (exclusive with bucket path)
    int* pos  = (int*)((char*)d_ws + off_ebuf);
    int* esrc = pos + N;

    const int doBf  = (ws_size >= req_main && N <= (1 << 20)) ? 1 : 0;
    const int doBkt = (ws_size >= req_bkt  && N <= (1 << 20)) ? 1 : 0;
    const int nConv  = (int)((ND / 8 + 255) / 256);
    const int nEdgeB = (int)(((long long)E / 4 + 255) / 256) + 1;
    const int nPrep  = 64 + (doBf ? nConv : 0) + nEdgeB;
    const int nPart  = (int)(((long long)E + PART_EB - 1) / PART_EB);

    hipMemsetAsync(cnt, 0, (size_t)N * sizeof(int), stream);
    prep_kernel<<<nPrep, 256, 0, stream>>>(W, Wt, h, hb, dst, cnt, E, ND, nConv, doBf);

    if (doBkt) {
        bucketsum_kernel<<<(nbuck + 15) / 16, 256, 0, stream>>>(cnt, bsumB, N, nbuck);
        scanS_kernel<<<1, 1024, 0, stream>>>(bsumB, gptr, bstart, nbuck);
        partition64_kernel<<<nPart, 256, 0, stream>>>(src, dst, gptr, ebuf, E, nbuck);
        if (doBf)
            fused512_bf<<<nbuck, 512, 0, stream>>>(h, hb, cnt, bstart, gptr, ebuf, Wt, b, out, N);
        else
            fused512_f32<<<nbuck, 512, 0, stream>>>(h, cnt, bstart, gptr, ebuf, Wt, b, out, N);
    } else {
        const int nb = (N + SCAN_CHUNK - 1) / SCAN_CHUNK;
        scanA_kernel<<<nb, 256, 0, stream>>>(cnt, pos, bsumB, N);
        scanB_fb_kernel<<<1, 1024, 0, stream>>>(bsumB, nb);
        fill_direct_kernel<<<nEdgeB, 256, 0, stream>>>(src, dst, pos, bsumB, esrc, E);
        fused_kernel_f32<<<(N + NPB - 1) / NPB, 256, 0, stream>>>(h, cnt, pos, bsumB, esrc, Wt, b, out, N);
    }
}

// Round 12
// 232.536 us; speedup vs baseline: 5.6750x; 5.6750x over previous
//
#include <hip/hip_runtime.h>

#define DIM 128
#define NPB 32          // nodes per block in fused (4 waves x 8 nodes)
#define SCAN_CHUNK 1024 // nodes per scanA block
#define BK2_BITS 9      // 512 nodes per partition bucket
#define PART_T 32       // edges per thread in partition
#define PART_EB (256 * PART_T)  // 8192 edges per partition block

typedef unsigned int   uint32;
typedef unsigned short uint16;

__device__ __forceinline__ uint16 f32_to_bf16_rne(float f) {
    uint32 u = __float_as_uint(f);
    u += 0x7fffu + ((u >> 16) & 1u);
    return (uint16)(u >> 16);
}

// ===========================================================================
// prep: [0,64) transpose W ; [64,64+nConv) h->bf16 ; rest: per-node histogram
// ===========================================================================
__global__ __launch_bounds__(256) void prep_kernel(
    const float* __restrict__ W, float* __restrict__ Wt,
    const float* __restrict__ h, uint16* __restrict__ hb,
    const int* __restrict__ dst, int* __restrict__ cnt,
    int E, long long ND, int nConv, int doConv)
{
    const int bid = blockIdx.x;
    const int tid = threadIdx.x;
    if (bid < 64) {
        const int i = bid * 256 + tid;
        const int j = i >> 7, d = i & 127;
        Wt[d * DIM + j] = W[i];
    } else if (doConv && bid < 64 + nConv) {
        const long long base = ((long long)(bid - 64) * 256 + tid) * 8;
        if (base + 8 <= ND) {
            const float4 a = *(const float4*)&h[base];
            const float4 c = *(const float4*)&h[base + 4];
            uint4 v;
            v.x = (uint32)f32_to_bf16_rne(a.x) | ((uint32)f32_to_bf16_rne(a.y) << 16);
            v.y = (uint32)f32_to_bf16_rne(a.z) | ((uint32)f32_to_bf16_rne(a.w) << 16);
            v.z = (uint32)f32_to_bf16_rne(c.x) | ((uint32)f32_to_bf16_rne(c.y) << 16);
            v.w = (uint32)f32_to_bf16_rne(c.z) | ((uint32)f32_to_bf16_rne(c.w) << 16);
            *(uint4*)&hb[base] = v;
        }
    } else {
        const int hbase = 64 + (doConv ? nConv : 0);
        const long long e = ((long long)(bid - hbase) * 256 + tid) * 4;
        if (e + 4 <= E) {
            const int4 d4 = *(const int4*)&dst[e];
            atomicAdd(&cnt[d4.x], 1);
            atomicAdd(&cnt[d4.y], 1);
            atomicAdd(&cnt[d4.z], 1);
            atomicAdd(&cnt[d4.w], 1);
        } else {
            for (long long k = e; k < E && k < e + 4; ++k) atomicAdd(&cnt[dst[k]], 1);
        }
    }
}

// ---- scanA: per-chunk local exclusive scan + chunk totals -----------------
__global__ __launch_bounds__(256) void scanA_kernel(const int* __restrict__ cnt,
                                                    int* __restrict__ pos,
                                                    int* __restrict__ bsum, int N)
{
    __shared__ int ts[256];
    const int t = threadIdx.x;
    const int base = blockIdx.x * SCAN_CHUNK + t * 4;
    int v[4];
    int s = 0;
#pragma unroll
    for (int k = 0; k < 4; ++k) {
        v[k] = (base + k < N) ? cnt[base + k] : 0;
        s += v[k];
    }
    ts[t] = s;
    __syncthreads();
    for (int off = 1; off < 256; off <<= 1) {
        int x = (t >= off) ? ts[t - off] : 0;
        __syncthreads();
        ts[t] += x;
        __syncthreads();
    }
    int run = (t == 0) ? 0 : ts[t - 1];
    if (t == 255) bsum[blockIdx.x] = ts[255];
#pragma unroll
    for (int k = 0; k < 4; ++k) {
        if (base + k < N) pos[base + k] = run;   // LOCAL exclusive START (never mutated)
        run += v[k];
    }
}

// ---- scanB: excl-scan chunk totals + init bucket base/append pointers -----
__global__ __launch_bounds__(1024) void scanB_kernel(int* __restrict__ bsum, int nb,
                                                     const int* __restrict__ pos,
                                                     int* __restrict__ gptr,
                                                     int* __restrict__ bstart, int nbuck)
{
    __shared__ int ts[1024];
    const int t = threadIdx.x;
    ts[t] = (t < nb) ? bsum[t] : 0;
    __syncthreads();
    for (int off = 1; off < 1024; off <<= 1) {
        int x = (t >= off) ? ts[t - off] : 0;
        __syncthreads();
        ts[t] += x;
        __syncthreads();
    }
    if (t < nb) bsum[t] = (t == 0) ? 0 : ts[t - 1];   // chunk global offsets
    for (int bk = t; bk < nbuck; bk += 1024) {
        const int chunk = bk >> 1;                    // (bk<<9)>>10
        const int ec = (chunk == 0) ? 0 : ts[chunk - 1];
        const int st = ec + pos[bk << BK2_BITS];
        gptr[bk]   = st;   // mutable append pointer (partition)
        bstart[bk] = st;   // immutable copy (csrfill)
    }
}

// ---- partition: LDS-staged radix partition; ebuf packed src|dloc<<20 ------
__global__ __launch_bounds__(256) void partition_kernel(
    const int* __restrict__ src, const int* __restrict__ dst,
    int* __restrict__ gptr, uint32* __restrict__ ebuf, int E, int nbuck)
{
    __shared__ int hist[256];     // nbuck <= 256
    const int t = threadIdx.x;
    const long long e0 = (long long)blockIdx.x * PART_EB;

    for (int i = t; i < 256; i += 256) hist[i] = 0;
    __syncthreads();

#pragma unroll 1
    for (int j = 0; j < PART_T / 4; ++j) {
        const long long be = e0 + ((long long)(j * 256 + t)) * 4;
        if (be + 4 <= E) {
            const int4 d4 = *(const int4*)&dst[be];
            atomicAdd(&hist[d4.x >> BK2_BITS], 1);
            atomicAdd(&hist[d4.y >> BK2_BITS], 1);
            atomicAdd(&hist[d4.z >> BK2_BITS], 1);
            atomicAdd(&hist[d4.w >> BK2_BITS], 1);
        } else {
            for (long long k = be; k < E && k < be + 4; ++k)
                atomicAdd(&hist[dst[k] >> BK2_BITS], 1);
        }
    }
    __syncthreads();

    for (int i = t; i < nbuck; i += 256) {
        const int c = hist[i];
        hist[i] = (c > 0) ? atomicAdd(&gptr[i], c) : 0;
    }
    __syncthreads();

#pragma unroll 1
    for (int j = 0; j < PART_T / 4; ++j) {
        const long long be = e0 + ((long long)(j * 256 + t)) * 4;
        if (be + 4 <= E) {
            const int4 s4 = *(const int4*)&src[be];
            const int4 d4 = *(const int4*)&dst[be];
            int sl;
            sl = atomicAdd(&hist[d4.x >> BK2_BITS], 1);
            ebuf[sl] = (uint32)s4.x | (((uint32)d4.x & 511u) << 20);
            sl = atomicAdd(&hist[d4.y >> BK2_BITS], 1);
            ebuf[sl] = (uint32)s4.y | (((uint32)d4.y & 511u) << 20);
            sl = atomicAdd(&hist[d4.z >> BK2_BITS], 1);
            ebuf[sl] = (uint32)s4.z | (((uint32)d4.z & 511u) << 20);
            sl = atomicAdd(&hist[d4.w >> BK2_BITS], 1);
            ebuf[sl] = (uint32)s4.w | (((uint32)d4.w & 511u) << 20);
        } else {
            for (long long k = be; k < E && k < be + 4; ++k) {
                const int d = dst[k];
                const int sl = atomicAdd(&hist[d >> BK2_BITS], 1);
                ebuf[sl] = (uint32)src[k] | (((uint32)d & 511u) << 20);
            }
        }
    }
}

// ---- csrfill: one block per bucket; per-node counters live in LDS ---------
// Global pos is NOT mutated (stays = local starts) — fused uses pos+bsum.
__global__ __launch_bounds__(256) void csrfill_kernel(
    const uint32* __restrict__ ebuf, const int* __restrict__ bstart,
    const int* __restrict__ gptr, const int* __restrict__ bsum,
    const int* __restrict__ pos, int* __restrict__ esrc, int N)
{
    __shared__ int lcnt[1 << BK2_BITS];   // 512 ints
    const int b = blockIdx.x;
    const int t = threadIdx.x;
    const int nbase = b << BK2_BITS;
    const int bsumC = bsum[b >> 1];       // bucket fits in one 1024-chunk
#pragma unroll
    for (int k = 0; k < (1 << BK2_BITS) / 256; ++k) {
        const int i = t + k * 256;
        lcnt[i] = (nbase + i < N) ? pos[nbase + i] : 0;
    }
    __syncthreads();
    const int start = bstart[b];
    const int end   = gptr[b];
    for (int i = start + t; i < end; i += 256) {
        const uint32 p = ebuf[i];
        const int s    = (int)(p & 0xFFFFFu);
        const int dloc = (int)(p >> 20);
        const int slot = atomicAdd(&lcnt[dloc], 1) + bsumC;
        esrc[slot] = s;
    }
}

// ===========================================================================
// Fused aggregate + ReLU(agg @ W^T + b).  bf16-gather, 4-deep load pipeline.
//   Round 9/10 post-mortem: gather is latency-bound at ~1 outstanding load
//   per wave. Here edge k is consumed while loads k+4..k+7 are in flight
//   (named regs u0..u3, compiler emits s_waitcnt vmcnt(3)) — 4x MLP with
//   zero extra iterations and unchanged FP accumulation order.
//   NOTE: #pragma unroll 1 on the d4 GEMM loop is load-bearing — full unroll
//   blows past 256 VGPRs and spills ~3.5 GB to scratch (rounds 2-3).
// ===========================================================================
__global__ __launch_bounds__(256) void fused_kernel_bf(
    const float* __restrict__ h, const uint16* __restrict__ hb,
    const int* __restrict__ cnt, const int* __restrict__ pos,
    const int* __restrict__ bsum, const int* __restrict__ esrc,
    const float* __restrict__ Wt, const float* __restrict__ bias,
    float* __restrict__ out, int N)
{
    __shared__ float row_lds[NPB][DIM];   // 16 KB

    const int lane = threadIdx.x & 63;
    const int w    = threadIdx.x >> 6;
    const int nbase = blockIdx.x * NPB + w * 8;
    const int col2 = lane * 2;
    const uint32* __restrict__ hb32 = (const uint32*)hb;   // 64 dwords/row

#define LOADK(uX, kk) { const int s_ = __shfl(e_reg, (kk), 64); \
                        uX = hb32[((uint32)s_ << 6) | (uint32)lane]; }
#define ACC(uX) { ax += __uint_as_float(uX << 16); \
                  ay += __uint_as_float(uX & 0xffff0000u); }

    // ---- Phase 1: aggregate 8 rows into LDS --------------------------------
#pragma unroll 1
    for (int i = 0; i < 8; ++i) {
        const int node = nbase + i;            // wave-uniform
        if (node >= N) break;
        const int deg = cnt[node];
        float ax, ay;
        if (deg == 0) {
            const float2 v = *(const float2*)&h[(size_t)node * DIM + col2];
            ax = v.x; ay = v.y;
        } else {
            const int start = pos[node] + bsum[node >> 10];   // pos = starts
            ax = 0.f; ay = 0.f;
            int base = 0;
#pragma unroll 1
            while (base < deg) {
                const int chunk = (deg - base < 64) ? (deg - base) : 64;
                int e_reg = 0;
                if (lane < chunk) e_reg = esrc[start + base + lane];
                int k = 0;
                if (chunk >= 4) {
                    uint32 u0, u1, u2, u3;
                    LOADK(u0, 0) LOADK(u1, 1) LOADK(u2, 2) LOADK(u3, 3)
#pragma unroll 1
                    for (; k + 8 <= chunk; k += 4) {
                        ACC(u0) LOADK(u0, k + 4)
                        ACC(u1) LOADK(u1, k + 5)
                        ACC(u2) LOADK(u2, k + 6)
                        ACC(u3) LOADK(u3, k + 7)
                    }
                    ACC(u0) ACC(u1) ACC(u2) ACC(u3)
                    k += 4;
                }
#pragma unroll 1
                for (; k < chunk; ++k) {
                    uint32 u;
                    LOADK(u, k)
                    ACC(u)
                }
                base += chunk;
            }
            const float inv = 1.0f / (float)deg;
            ax *= inv; ay *= inv;
        }
        *(float2*)&row_lds[w * 8 + i][col2] = make_float2(ax, ay);
    }
    __syncthreads();

#undef LOADK
#undef ACC

    // ---- Phase 2: GEMM out = ReLU(row @ W^T + b) ---------------------------
    const float2 bb = *(const float2*)&bias[col2];
    float acc0[8], acc1[8];
#pragma unroll
    for (int n = 0; n < 8; ++n) { acc0[n] = bb.x; acc1[n] = bb.y; }

#pragma unroll 1
    for (int d4 = 0; d4 < DIM; d4 += 4) {
        float4 a[8];
#pragma unroll
        for (int n = 0; n < 8; ++n)
            a[n] = *(const float4*)&row_lds[w * 8 + n][d4];   // broadcast
#pragma unroll
        for (int dd = 0; dd < 4; ++dd) {
            const float2 wt = *(const float2*)&Wt[(d4 + dd) * DIM + col2];
#pragma unroll
            for (int n = 0; n < 8; ++n) {
                const float av = dd == 0 ? a[n].x : dd == 1 ? a[n].y
                               : dd == 2 ? a[n].z : a[n].w;
                acc0[n] = fmaf(av, wt.x, acc0[n]);
                acc1[n] = fmaf(av, wt.y, acc1[n]);
            }
        }
    }

#pragma unroll
    for (int n = 0; n < 8; ++n) {
        const int node = nbase + n;
        if (node < N) {
            *(float2*)&out[(size_t)node * DIM + col2] =
                make_float2(fmaxf(acc0[n], 0.0f), fmaxf(acc1[n], 0.0f));
        }
    }
}

// ===========================================================================
// Fallback path (ws can't hold ebuf/hb, or N too large for packing):
// direct fill (pos mutated to ends) + f32 CSR gather.
// ===========================================================================
__global__ __launch_bounds__(256) void fill_direct_kernel(
    const int* __restrict__ src, const int* __restrict__ dst,
    int* __restrict__ pos, const int* __restrict__ bsum,
    int* __restrict__ esrc, int E)
{
    const long long e = ((long long)blockIdx.x * 256 + threadIdx.x) * 4;
    if (e + 4 <= E) {
        const int4 s4 = *(const int4*)&src[e];
        const int4 d4 = *(const int4*)&dst[e];
        int sl;
        sl = atomicAdd(&pos[d4.x], 1); esrc[sl + bsum[d4.x >> 10]] = s4.x;
        sl = atomicAdd(&pos[d4.y], 1); esrc[sl + bsum[d4.y >> 10]] = s4.y;
        sl = atomicAdd(&pos[d4.z], 1); esrc[sl + bsum[d4.z >> 10]] = s4.z;
        sl = atomicAdd(&pos[d4.w], 1); esrc[sl + bsum[d4.w >> 10]] = s4.w;
    } else {
        for (long long k = e; k < E && k < e + 4; ++k) {
            const int d = dst[k];
            const int sl = atomicAdd(&pos[d], 1);
            esrc[sl + bsum[d >> 10]] = src[k];
        }
    }
}

__global__ __launch_bounds__(256) void fused_kernel_f32(
    const float* __restrict__ h,
    const int* __restrict__ cnt, const int* __restrict__ pos,
    const int* __restrict__ bsum, const int* __restrict__ esrc,
    const float* __restrict__ Wt, const float* __restrict__ bias,
    float* __restrict__ out, int N)
{
    __shared__ float row_lds[NPB][DIM];
    const int lane = threadIdx.x & 63;
    const int w    = threadIdx.x >> 6;
    const int nbase = blockIdx.x * NPB + w * 8;
    const int col2 = lane * 2;

#pragma unroll 1
    for (int i = 0; i < 8; ++i) {
        const int node = nbase + i;
        if (node >= N) break;
        const int deg = cnt[node];
        float ax, ay;
        if (deg == 0) {
            const float2 v = *(const float2*)&h[(size_t)node * DIM + col2];
            ax = v.x; ay = v.y;
        } else {
            const int start = pos[node] - deg + bsum[node >> 10];  // pos = ends here
            ax = 0.f; ay = 0.f;
#pragma unroll 4
            for (int k = 0; k < deg; ++k) {
                const int s = esrc[start + k];
                const float2 v = *(const float2*)&h[(size_t)s * DIM + col2];
                ax += v.x; ay += v.y;
            }
            const float inv = 1.0f / (float)deg;
            ax *= inv; ay *= inv;
        }
        *(float2*)&row_lds[w * 8 + i][col2] = make_float2(ax, ay);
    }
    __syncthreads();

    const float2 bb = *(const float2*)&bias[col2];
    float acc0[8], acc1[8];
#pragma unroll
    for (int n = 0; n < 8; ++n) { acc0[n] = bb.x; acc1[n] = bb.y; }

#pragma unroll 1
    for (int d4 = 0; d4 < DIM; d4 += 4) {
        float4 a[8];
#pragma unroll
        for (int n = 0; n < 8; ++n)
            a[n] = *(const float4*)&row_lds[w * 8 + n][d4];
#pragma unroll
        for (int dd = 0; dd < 4; ++dd) {
            const float2 wt = *(const float2*)&Wt[(d4 + dd) * DIM + col2];
#pragma unroll
            for (int n = 0; n < 8; ++n) {
                const float av = dd == 0 ? a[n].x : dd == 1 ? a[n].y
                               : dd == 2 ? a[n].z : a[n].w;
                acc0[n] = fmaf(av, wt.x, acc0[n]);
                acc1[n] = fmaf(av, wt.y, acc1[n]);
            }
        }
    }

#pragma unroll
    for (int n = 0; n < 8; ++n) {
        const int node = nbase + n;
        if (node < N) {
            *(float2*)&out[(size_t)node * DIM + col2] =
                make_float2(fmaxf(acc0[n], 0.0f), fmaxf(acc1[n], 0.0f));
        }
    }
}

// ===========================================================================
extern "C" void kernel_launch(void* const* d_in, const int* in_sizes, int n_in,
                              void* d_out, int out_size, void* d_ws, size_t ws_size,
                              hipStream_t stream)
{
    const float* h  = (const float*)d_in[0];
    const int* src  = (const int*)d_in[1];
    const int* dst  = (const int*)d_in[2];
    const float* W  = (const float*)d_in[3];
    const float* b  = (const float*)d_in[4];
    float* out = (float*)d_out;

    const int N = in_sizes[0] / DIM;
    const int E = in_sizes[1];
    const long long ND = (long long)N * DIM;
    const int nb = (N + SCAN_CHUNK - 1) / SCAN_CHUNK;
    const int nbuck = (N + (1 << BK2_BITS) - 1) >> BK2_BITS;

    // Workspace layout
    const size_t off_cnt  = 0;
    const size_t off_pos  = (size_t)N * sizeof(int);
    const size_t off_esrc = off_pos + (size_t)N * sizeof(int);
    const size_t off_wt   = off_esrc + (size_t)E * sizeof(int);
    const size_t off_bsum = off_wt + (size_t)DIM * DIM * sizeof(float);
    const size_t off_gp   = off_bsum + 4096;
    const size_t off_bs2  = off_gp + 1024;
    const size_t off_hb   = (off_bs2 + 1024 + 255) & ~(size_t)255;
    const size_t off_ebuf = (off_hb + (size_t)ND * sizeof(uint16) + 255) & ~(size_t)255;
    const size_t req_bf   = off_ebuf;                                   // hb only
    const size_t req_full = off_ebuf + (size_t)E * sizeof(uint32);      // + packed ebuf

    int*    cnt    = (int*)((char*)d_ws + off_cnt);
    int*    pos    = (int*)((char*)d_ws + off_pos);
    int*    esrc   = (int*)((char*)d_ws + off_esrc);
    float*  Wt     = (float*)((char*)d_ws + off_wt);
    int*    bsum   = (int*)((char*)d_ws + off_bsum);
    int*    gptr   = (int*)((char*)d_ws + off_gp);
    int*    bstart = (int*)((char*)d_ws + off_bs2);
    uint16* hb     = (uint16*)((char*)d_ws + off_hb);
    uint32* ebuf   = (uint32*)((char*)d_ws + off_ebuf);

    const int packOK   = (N <= (1 << 20)) && (nbuck <= 256);
    const int doConv   = (ws_size >= req_bf) ? 1 : 0;
    const int doBucket = (ws_size >= req_full && packOK && doConv) ? 1 : 0;
    const int nConv  = (int)((ND / 8 + 255) / 256);
    const int nEdgeB = (int)(((long long)E / 4 + 255) / 256) + 1;
    const int nPrep  = 64 + (doConv ? nConv : 0) + nEdgeB;
    const int nPart  = (int)(((long long)E + PART_EB - 1) / PART_EB);

    hipMemsetAsync(cnt, 0, (size_t)N * sizeof(int), stream);
    prep_kernel<<<nPrep, 256, 0, stream>>>(W, Wt, h, hb, dst, cnt, E, ND, nConv, doConv);
    scanA_kernel<<<nb, 256, 0, stream>>>(cnt, pos, bsum, N);
    scanB_kernel<<<1, 1024, 0, stream>>>(bsum, nb, pos, gptr, bstart, nbuck);

    if (doBucket) {
        partition_kernel<<<nPart, 256, 0, stream>>>(src, dst, gptr, ebuf, E, nbuck);
        csrfill_kernel<<<nbuck, 256, 0, stream>>>(ebuf, bstart, gptr, bsum, pos, esrc, N);
        fused_kernel_bf<<<(N + NPB - 1) / NPB, 256, 0, stream>>>(h, hb, cnt, pos, bsum, esrc, Wt, b, out, N);
    } else {
        fill_direct_kernel<<<nEdgeB, 256, 0, stream>>>(src, dst, pos, bsum, esrc, E);
        fused_kernel_f32<<<(N + NPB - 1) / NPB, 256, 0, stream>>>(h, cnt, pos, bsum, esrc, Wt, b, out, N);
    }
}